// Round 8
// baseline (224.428 us; speedup 1.0000x reference)
//
#include <hip/hip_runtime.h>

#define N_NODES 100000
#define N_EDGES 3200000
#define IN_DIM  29
#define HID_DIM 64
#define NBUCK   391            // ceil(N / 256)
#define BNODES  256            // dst nodes per bucket
#define CAP     10496          // slots/bucket (mult of 16); mean ~9650, +7.6 sigma
#define PEPT    16
#define PEPB    16384          // 1024 threads * 16 edges
#define PSTAGE  22272          // >= NBUCK*15 + PEPB = 22249

// ---- ws layout (4-byte units) ---------------------------------------------
#define OFF_CUR   0            // gcursor[NBUCK] (pad to 512)
#define OFF_ROWS  512          // rowStart[N]
#define OFF_ROWE  100512       // rowEnd[N]  (PADDED end)
#define OFF_DINV  200512       // dinv[N]
#define OFF_ZS    300512       // zs[2N+2]; row N = sentinel zeros
#define OFF_EBUF  500544       // ebuf[NBUCK*CAP] = 4,103,936
#define OFF_XS    4604480      // xs bf16[(N+1) rows * 16 uints], 128B aligned

static __device__ __forceinline__ unsigned short f2bf(float f) {
    unsigned u = __float_as_uint(f);
    u += 0x7fffu + ((u >> 16) & 1u);   // RNE
    return (unsigned short)(u >> 16);
}

// unpack 8 bf16 (one uint4 = 16B) into float8 accumulator (two float4)
static __device__ __forceinline__ void upk8(float4& L, float4& H, uint4 a) {
    L.x += __uint_as_float(a.x << 16); L.y += __uint_as_float(a.x & 0xFFFF0000u);
    L.z += __uint_as_float(a.y << 16); L.w += __uint_as_float(a.y & 0xFFFF0000u);
    H.x += __uint_as_float(a.z << 16); H.y += __uint_as_float(a.z & 0xFFFF0000u);
    H.z += __uint_as_float(a.w << 16); H.w += __uint_as_float(a.w & 0xFFFF0000u);
}

// -- partition: LDS counting-sort per block, FULL-LINE coalesced writeback ---
__global__ __launch_bounds__(1024) void partition_kernel(const int* __restrict__ ei,
        int* __restrict__ gcursor, int* __restrict__ ebuf) {
    __shared__ int lhist[NBUCK];
    __shared__ int lcur[NBUCK];
    __shared__ int gbase[NBUCK];
    __shared__ int soff[NBUCK];
    __shared__ int sc[NBUCK];
    __shared__ int stage[PSTAGE];                      // 87 KB
    int tid = threadIdx.x;
    for (int i = tid; i < NBUCK; i += 1024) lhist[i] = 0;
    __syncthreads();

    int base = blockIdx.x * PEPB + tid * PEPT;         // 16-aligned; E%16==0
    bool valid = (base < N_EDGES);
    if (valid) {                                       // pass 1: histogram
        const int4* dp = (const int4*)(ei + N_EDGES + base);
        #pragma unroll
        for (int q = 0; q < 4; ++q) {
            int4 t = dp[q];
            atomicAdd(&lhist[t.x >> 8], 1); atomicAdd(&lhist[t.y >> 8], 1);
            atomicAdd(&lhist[t.z >> 8], 1); atomicAdd(&lhist[t.w >> 8], 1);
        }
    }
    __syncthreads();
    int c = 0, p = 0;                                  // scan 16-padded counts
    if (tid < NBUCK) { c = lhist[tid]; p = (c + 15) & ~15; sc[tid] = p; }
    __syncthreads();
    for (int off = 1; off < NBUCK; off <<= 1) {
        int t = 0;
        if (tid < NBUCK && tid >= off) t = sc[tid - off];
        __syncthreads();
        if (tid < NBUCK) sc[tid] += t;
        __syncthreads();
    }
    if (tid < NBUCK) {
        int so = sc[tid] - p;
        soff[tid] = so;
        lcur[tid] = so;
        gbase[tid] = p ? (tid * CAP + atomicAdd(&gcursor[tid], p)) : 0; // 64B-aligned claim
    }
    __syncthreads();
    if (valid) {                                       // pass 2: place into LDS
        const int4* dp = (const int4*)(ei + N_EDGES + base);
        const int4* sp = (const int4*)(ei + base);
        #pragma unroll
        for (int q = 0; q < 4; ++q) {
            int4 d = dp[q];
            int4 s = sp[q];
            int pos;
            pos = atomicAdd(&lcur[d.x >> 8], 1); stage[pos] = s.x | ((d.x & 255) << 17);
            pos = atomicAdd(&lcur[d.y >> 8], 1); stage[pos] = s.y | ((d.y & 255) << 17);
            pos = atomicAdd(&lcur[d.z >> 8], 1); stage[pos] = s.z | ((d.z & 255) << 17);
            pos = atomicAdd(&lcur[d.w >> 8], 1); stage[pos] = s.w | ((d.w & 255) << 17);
        }
    }
    __syncthreads();
    if (tid < NBUCK) {                                 // sentinel-fill pad slots
        int endReal = lcur[tid];
        int endPad  = soff[tid] + (((lhist[tid]) + 15) & ~15);
        for (int k = endReal; k < endPad; ++k) stage[k] = -1;
    }
    __syncthreads();
    int wv = tid >> 6, ln = tid & 63;                  // full-line writeback
    for (int b = wv; b < NBUCK; b += 16) {
        int np = (lhist[b] + 15) & ~15;
        int so = soff[b], gb = gbase[b];
        for (int k = ln; k < np; k += 64)
            ebuf[gb + k] = stage[so + k];
    }
}

// ---- bucketsort (round-6 proven): count, scan, place into LDS, -------------
// ---- coalesced full-line writeback; xs bf16 conversion fused at the end ----
__global__ __launch_bounds__(1024) void bucketsort_kernel(const int* __restrict__ gcursor,
        int* __restrict__ ebuf, int* __restrict__ rowStart, int* __restrict__ rowEnd,
        float* __restrict__ dinv, const float* __restrict__ x,
        unsigned int* __restrict__ xsb, float* __restrict__ zs) {
    __shared__ int   cnt[BNODES];
    __shared__ int   cur[BNODES];
    __shared__ float dls[BNODES];
    __shared__ int   stage[CAP];                       // 41 KB
    __shared__ int   szp_sh;
    int b = blockIdx.x, tid = threadIdx.x;
    if (tid < BNODES) cnt[tid] = 0;
    __syncthreads();
    int base = b * CAP;
    int size = gcursor[b];                             // incl. partition pads

    for (int j = tid; j < size; j += 1024) {           // pass 1: count
        unsigned p = (unsigned)ebuf[base + j];
        if (p != 0xFFFFFFFFu) atomicAdd(&cnt[p >> 17], 1);
    }
    __syncthreads();

    int v = 0, vp = 0;
    if (tid < BNODES) { v = cnt[tid]; vp = (v + 7) & ~7; cur[tid] = vp; }
    __syncthreads();
    for (int off = 1; off < BNODES; off <<= 1) {       // inclusive scan of vp
        int t = 0;
        if (tid < BNODES && tid >= off) t = cur[tid - off];
        __syncthreads();
        if (tid < BNODES) cur[tid] += t;
        __syncthreads();
    }
    if (tid < BNODES) {
        int excl = cur[tid] - vp;
        int node = b * BNODES + tid;
        if (node < N_NODES) {
            rowStart[node] = base + excl;
            rowEnd[node]   = base + excl + vp;         // padded end
            float dn = rsqrtf((float)v + 1.0f);        // +1 = self loop (REAL deg)
            dinv[node] = dn;
            dls[tid] = dn;
        }
        if (tid == BNODES - 1) szp_sh = cur[tid];      // total node-padded size
        cur[tid] = excl;                               // becomes cursor
        for (int p2 = excl + v; p2 < excl + vp; ++p2)  // fill node-pad slots
            stage[p2] = N_NODES;                       // sentinel -> zero row
    }
    __syncthreads();

    for (int j = tid; j < size; j += 1024) {           // pass 2: place into LDS
        unsigned p = (unsigned)ebuf[base + j];
        if (p != 0xFFFFFFFFu) {
            int pos = atomicAdd(&cur[p >> 17], 1);
            stage[pos] = p & 0x1FFFF;
        }
    }
    __syncthreads();
    int szp = szp_sh;
    for (int j = tid; j < szp; j += 1024)              // coalesced writeback
        ebuf[base + j] = stage[j];

    // xs = bf16(x * dinv), padded to 32 features; 2 features per uint
    for (int i = tid; i < BNODES * 16; i += 1024) {
        int dl = i >> 4, kp = i & 15;
        int nd = b * BNODES + dl;
        if (nd < N_NODES) {
            float dn = dls[dl];
            int k0 = kp * 2, k1 = k0 + 1;
            float f0 = (k0 < IN_DIM) ? x[nd * IN_DIM + k0] * dn : 0.0f;
            float f1 = (k1 < IN_DIM) ? x[nd * IN_DIM + k1] * dn : 0.0f;
            xsb[(size_t)nd * 16 + kp] = (unsigned)f2bf(f0) | ((unsigned)f2bf(f1) << 16);
        } else if (nd == N_NODES) {
            xsb[(size_t)nd * 16 + kp] = 0u;            // sentinel zero row
        }
    }
    if (b == 0 && tid == 0) {                          // zs sentinel (agg2 pads)
        zs[2 * N_NODES]     = 0.0f;
        zs[2 * N_NODES + 1] = 0.0f;
    }
}

// --- fused: 16 streams x 4 lanes, uint4 gathers (4 addrs/edge, not 8) -------
#define XOFF(i) ((((unsigned)(i)) << 6) | (m << 4))

#define PREP(P, rs, re)                                                  \
    int P##i0, P##i1, P##i2;                                             \
    {                                                                    \
        int relim = max((re) - 1, (rs));                                 \
        int j0 = (rs) + q;                                               \
        int t0 = ebuf[min(j0,      relim)];                              \
        int t1 = ebuf[min(j0 + 16, relim)];                              \
        int t2 = ebuf[min(j0 + 32, relim)];                              \
        P##i0 = (j0      < (re)) ? t0 : N_NODES;                         \
        P##i1 = (j0 + 16 < (re)) ? t1 : N_NODES;                         \
        P##i2 = (j0 + 32 < (re)) ? t2 : N_NODES;                         \
    }

#define GATH(G, P)                                                      \
    uint4 G##0 = *(const uint4*)(xb + XOFF(P##i0));                     \
    uint4 G##1 = *(const uint4*)(xb + XOFF(P##i1));                     \
    uint4 G##2 = *(const uint4*)(xb + XOFF(P##i2));

#define UNP(L, H, G)                                                    \
    upk8(L, H, G##0); upk8(L, H, G##1); upk8(L, H, G##2);

#define TAIL(L, H, rs, re)                                              \
    {                                                                   \
        int j = (rs) + q + 48;                                          \
        while (j < (re)) {            /* rare: P(deg>48) ~ 0.3% */      \
            int s = ebuf[j];                                            \
            uint4 a = *(const uint4*)(xb + XOFF(s));                    \
            upk8(L, H, a);                                              \
            j += 16;                                                    \
        }                                                               \
    }

static __device__ __forceinline__ void fold8(float4& L, float4& H) {
    #pragma unroll
    for (int msk = 4; msk <= 32; msk <<= 1) {          // fold 16 q-streams
        L.x += __shfl_xor(L.x, msk); L.y += __shfl_xor(L.y, msk);
        L.z += __shfl_xor(L.z, msk); L.w += __shfl_xor(L.w, msk);
        H.x += __shfl_xor(H.x, msk); H.y += __shfl_xor(H.y, msk);
        H.z += __shfl_xor(H.z, msk); H.w += __shfl_xor(H.w, msk);
    }
}

// two nodes' MLPs fused: shared w1s reads; lane m=lane&3 holds feats 8m..8m+7
static __device__ __forceinline__ void mlp2_store(
        float4 LA, float4 HA, float4 LB, float4 HB,
        int nodeA, int nodeB, int lane,
        const float* w1s, const float* b1s, const float* w2s,
        const float* __restrict__ dinv, float* __restrict__ zs) {
    float dnA = dinv[nodeA], dnB = dinv[nodeB];
    LA.x *= dnA; LA.y *= dnA; LA.z *= dnA; LA.w *= dnA;
    HA.x *= dnA; HA.y *= dnA; HA.z *= dnA; HA.w *= dnA;
    LB.x *= dnB; LB.y *= dnB; LB.z *= dnB; LB.w *= dnB;
    HB.x *= dnB; HB.y *= dnB; HB.z *= dnB; HB.w *= dnB;

    float hA = b1s[lane], hB = b1s[lane];
    #pragma unroll
    for (int kk = 0; kk < IN_DIM; ++kk) {              // shared weight read
        float w = w1s[kk * HID_DIM + lane];
        int r = kk & 7;
        float cA = (r == 0) ? LA.x : (r == 1) ? LA.y : (r == 2) ? LA.z
                 : (r == 3) ? LA.w : (r == 4) ? HA.x : (r == 5) ? HA.y
                 : (r == 6) ? HA.z : HA.w;
        float cB = (r == 0) ? LB.x : (r == 1) ? LB.y : (r == 2) ? LB.z
                 : (r == 3) ? LB.w : (r == 4) ? HB.x : (r == 5) ? HB.y
                 : (r == 6) ? HB.z : HB.w;
        hA = fmaf(__shfl(cA, kk >> 3), w, hA);
        hB = fmaf(__shfl(cB, kk >> 3), w, hB);
    }
    hA = fmaxf(hA, 0.0f); hB = fmaxf(hB, 0.0f);

    float zA0 = hA * w2s[lane * 2 + 0], zA1 = hA * w2s[lane * 2 + 1];
    float zB0 = hB * w2s[lane * 2 + 0], zB1 = hB * w2s[lane * 2 + 1];
    #pragma unroll
    for (int off = 32; off > 0; off >>= 1) {
        zA0 += __shfl_down(zA0, off); zA1 += __shfl_down(zA1, off);
        zB0 += __shfl_down(zB0, off); zB1 += __shfl_down(zB1, off);
    }
    if (lane == 0) {                                   // pre-scale by src dinv
        float2 oA; oA.x = zA0 * dnA; oA.y = zA1 * dnA;
        float2 oB; oB.x = zB0 * dnB; oB.y = zB1 * dnB;
        *(float2*)(zs + nodeA * 2) = oA;
        *(float2*)(zs + nodeB * 2) = oB;
    }
}

__global__ __launch_bounds__(512) void fused_kernel(const unsigned int* __restrict__ xs_,
        const int* __restrict__ rowStart, const int* __restrict__ rowEnd,
        const int* __restrict__ ebuf, const float* __restrict__ dinv,
        const float* __restrict__ W1, const float* __restrict__ b1,
        const float* __restrict__ W2, float* __restrict__ zs) {
    __shared__ float w1s[IN_DIM * HID_DIM];
    __shared__ float b1s[HID_DIM];
    __shared__ float w2s[HID_DIM * 2];
    const int tid = threadIdx.x;
    for (int i = tid; i < IN_DIM * HID_DIM; i += 512) w1s[i] = W1[i];
    if (tid < HID_DIM) {
        b1s[tid] = b1[tid];
        w2s[tid * 2 + 0] = W2[tid * 2 + 0];
        w2s[tid * 2 + 1] = W2[tid * 2 + 1];
    }
    __syncthreads();

    const int lane = tid & 63;
    const int q = lane >> 2;                           // 16 streams
    const int m = lane & 3;                            // 4 x 16B per 64B row
    const char* xb = (const char*)xs_;
    const int n0 = blockIdx.x * 32 + (tid >> 6) * 4;   // 8 waves x 4 nodes; 3125*32=N

    const int rs0 = rowStart[n0+0], re0 = rowEnd[n0+0];
    const int rs1 = rowStart[n0+1], re1 = rowEnd[n0+1];
    const int rs2 = rowStart[n0+2], re2 = rowEnd[n0+2];
    const int rs3 = rowStart[n0+3], re3 = rowEnd[n0+3];

    // ---- pair pipeline: nodes {0,1} gather+reduce while {2,3} prefetch ----
    PREP(pa, rs0, re0)
    PREP(pb, rs1, re1)
    GATH(ga, pa)                                       // 6 insts, 16B/lane
    GATH(gb, pb)
    PREP(pc, rs2, re2)
    PREP(pd, rs3, re3)
    float4 LA = {0,0,0,0}, HA = {0,0,0,0}, LB = {0,0,0,0}, HB = {0,0,0,0};
    UNP(LA, HA, ga)
    TAIL(LA, HA, rs0, re0)
    UNP(LB, HB, gb)
    TAIL(LB, HB, rs1, re1)
    GATH(gc, pc)                                       // next pair in flight
    GATH(gd, pd)
    uint4 svA = *(const uint4*)(xb + XOFF(n0+0));      // self rows (broadcast)
    uint4 svB = *(const uint4*)(xb + XOFF(n0+1));
    fold8(LA, HA);
    fold8(LB, HB);
    upk8(LA, HA, svA);                                 // self added post-fold
    upk8(LB, HB, svB);
    mlp2_store(LA, HA, LB, HB, n0+0, n0+1, lane, w1s, b1s, w2s, dinv, zs);

    float4 LC = {0,0,0,0}, HC = {0,0,0,0}, LD = {0,0,0,0}, HD = {0,0,0,0};
    UNP(LC, HC, gc)
    TAIL(LC, HC, rs2, re2)
    UNP(LD, HD, gd)
    TAIL(LD, HD, rs3, re3)
    uint4 svC = *(const uint4*)(xb + XOFF(n0+2));
    uint4 svD = *(const uint4*)(xb + XOFF(n0+3));
    fold8(LC, HC);
    fold8(LD, HD);
    upk8(LC, HC, svC);
    upk8(LD, HD, svD);
    mlp2_store(LC, HC, LD, HD, n0+2, n0+3, lane, w1s, b1s, w2s, dinv, zs);
}

// ------- agg2: 16-lane group per node gathers zs (2x unroll) + finalize -----
__global__ __launch_bounds__(256) void agg2_kernel(const float* __restrict__ zs,
        const int* __restrict__ rowStart, const int* __restrict__ rowEnd,
        const int* __restrict__ ebuf, const float* __restrict__ dinv,
        const float* __restrict__ b2, float* __restrict__ out) {
    int tid = threadIdx.x;
    int node = blockIdx.x * 16 + (tid >> 4);
    if (node >= N_NODES) return;
    int gl = tid & 15;
    const float2* zs2 = (const float2*)zs;
    float a0 = 0.0f, a1 = 0.0f, c0 = 0.0f, c1 = 0.0f;
    int rs = rowStart[node], re = rowEnd[node];
    int j = rs + gl;
    for (; j + 16 < re; j += 32) {
        float2 za = zs2[ebuf[j]];
        float2 zb = zs2[ebuf[j + 16]];
        a0 += za.x; a1 += za.y;
        c0 += zb.x; c1 += zb.y;
    }
    if (j < re) {
        float2 za = zs2[ebuf[j]];
        a0 += za.x; a1 += za.y;
    }
    a0 += c0; a1 += c1;
    a0 += __shfl_xor(a0, 8); a1 += __shfl_xor(a1, 8);
    a0 += __shfl_xor(a0, 4); a1 += __shfl_xor(a1, 4);
    a0 += __shfl_xor(a0, 2); a1 += __shfl_xor(a1, 2);
    a0 += __shfl_xor(a0, 1); a1 += __shfl_xor(a1, 1);
    if (gl == 0) {
        float dn = dinv[node];
        float2 zself = zs2[node];
        float2 o;
        o.x = dn * (a0 + zself.x) + b2[0];
        o.y = dn * (a1 + zself.y) + b2[1];
        ((float2*)out)[node] = o;
    }
}

extern "C" void kernel_launch(void* const* d_in, const int* in_sizes, int n_in,
                              void* d_out, int out_size, void* d_ws, size_t ws_size,
                              hipStream_t stream) {
    const float* x  = (const float*)d_in[0];
    const int*   ei = (const int*)d_in[1];
    const float* W1 = (const float*)d_in[2];
    const float* b1 = (const float*)d_in[3];
    const float* W2 = (const float*)d_in[4];
    const float* b2 = (const float*)d_in[5];
    float* out = (float*)d_out;

    int*   wsi      = (int*)d_ws;
    float* wsf      = (float*)d_ws;
    int*   gcursor  = wsi + OFF_CUR;
    int*   rowStart = wsi + OFF_ROWS;
    int*   rowEnd   = wsi + OFF_ROWE;
    float* dinv     = wsf + OFF_DINV;
    float* zs       = wsf + OFF_ZS;
    int*   ebuf     = wsi + OFF_EBUF;
    unsigned int* xsb = (unsigned int*)(wsi + OFF_XS);

    hipMemsetAsync(gcursor, 0, NBUCK * sizeof(int), stream);
    partition_kernel<<<(N_EDGES + PEPB - 1) / PEPB, 1024, 0, stream>>>(ei, gcursor, ebuf);
    bucketsort_kernel<<<NBUCK, 1024, 0, stream>>>(gcursor, ebuf, rowStart, rowEnd, dinv, x, xsb, zs);
    fused_kernel<<<N_NODES / 32, 512, 0, stream>>>(xsb, rowStart, rowEnd, ebuf, dinv, W1, b1, W2, zs);
    agg2_kernel<<<(N_NODES + 15) / 16, 256, 0, stream>>>(zs, rowStart, rowEnd, ebuf, dinv, b2, out);
}

// Round 9
// 215.288 us; speedup vs baseline: 1.0425x; 1.0425x over previous
//
#include <hip/hip_runtime.h>

#define N_NODES 100000
#define N_EDGES 3200000
#define IN_DIM  29
#define HID_DIM 64
#define NBUCK   196            // ceil(N / 512) -> ONE round on 256 CUs
#define BNODES  512            // dst nodes per bucket (dl = 9 bits)
#define CAP     18944          // slots/bucket (x16); padded mean ~18.1k, +6 sigma
#define PEPT    16
#define PEPB    16384          // 1024 threads * 16 edges
#define PSTAGE  19328          // >= NBUCK*15 + PEPB = 19324

// ---- ws layout (4-byte units) ---------------------------------------------
#define OFF_CUR   0            // gcursor[NBUCK] (pad to 512)
#define OFF_ROWS  512          // rowStart[N]
#define OFF_ROWE  100512       // rowEnd[N]  (PADDED end)
#define OFF_DINV  200512       // dinv[N]
#define OFF_ZS    300512       // zs[2N+2]; row N = sentinel zeros
#define OFF_EBUF  500544       // ebuf[NBUCK*CAP] = 3,713,024
#define OFF_XS    4604480      // xs bf16[(N+1) rows * 16 uints], 128B aligned

static __device__ __forceinline__ unsigned short f2bf(float f) {
    unsigned u = __float_as_uint(f);
    u += 0x7fffu + ((u >> 16) & 1u);   // RNE
    return (unsigned short)(u >> 16);
}

static __device__ __forceinline__ void unpack_add(float4& acc, uint2 a) {
    acc.x += __uint_as_float(a.x << 16);
    acc.y += __uint_as_float(a.x & 0xFFFF0000u);
    acc.z += __uint_as_float(a.y << 16);
    acc.w += __uint_as_float(a.y & 0xFFFF0000u);
}

// -- partition: LDS counting-sort per block, FULL-LINE coalesced writeback ---
// Buckets of 512 dst nodes; packed src | dl<<17 (dl 9 bits). Pads = -1.
__global__ __launch_bounds__(1024) void partition_kernel(const int* __restrict__ ei,
        int* __restrict__ gcursor, int* __restrict__ ebuf) {
    __shared__ int lhist[NBUCK];
    __shared__ int lcur[NBUCK];
    __shared__ int gbase[NBUCK];
    __shared__ int soff[NBUCK];
    __shared__ int sc[NBUCK];
    __shared__ int stage[PSTAGE];                      // 77.3 KB
    int tid = threadIdx.x;
    for (int i = tid; i < NBUCK; i += 1024) lhist[i] = 0;
    __syncthreads();

    int base = blockIdx.x * PEPB + tid * PEPT;         // 16-aligned; E%16==0
    bool valid = (base < N_EDGES);
    if (valid) {                                       // pass 1: histogram
        const int4* dp = (const int4*)(ei + N_EDGES + base);
        #pragma unroll
        for (int q = 0; q < 4; ++q) {
            int4 t = dp[q];
            atomicAdd(&lhist[t.x >> 9], 1); atomicAdd(&lhist[t.y >> 9], 1);
            atomicAdd(&lhist[t.z >> 9], 1); atomicAdd(&lhist[t.w >> 9], 1);
        }
    }
    __syncthreads();
    int c = 0, p = 0;                                  // scan 16-padded counts
    if (tid < NBUCK) { c = lhist[tid]; p = (c + 15) & ~15; sc[tid] = p; }
    __syncthreads();
    for (int off = 1; off < NBUCK; off <<= 1) {
        int t = 0;
        if (tid < NBUCK && tid >= off) t = sc[tid - off];
        __syncthreads();
        if (tid < NBUCK) sc[tid] += t;
        __syncthreads();
    }
    if (tid < NBUCK) {
        int so = sc[tid] - p;
        soff[tid] = so;
        lcur[tid] = so;
        gbase[tid] = p ? (tid * CAP + atomicAdd(&gcursor[tid], p)) : 0; // 64B-aligned claim
    }
    __syncthreads();
    if (valid) {                                       // pass 2: place into LDS
        const int4* dp = (const int4*)(ei + N_EDGES + base);
        const int4* sp = (const int4*)(ei + base);
        #pragma unroll
        for (int q = 0; q < 4; ++q) {
            int4 d = dp[q];
            int4 s = sp[q];
            int pos;
            pos = atomicAdd(&lcur[d.x >> 9], 1); stage[pos] = s.x | ((d.x & 511) << 17);
            pos = atomicAdd(&lcur[d.y >> 9], 1); stage[pos] = s.y | ((d.y & 511) << 17);
            pos = atomicAdd(&lcur[d.z >> 9], 1); stage[pos] = s.z | ((d.z & 511) << 17);
            pos = atomicAdd(&lcur[d.w >> 9], 1); stage[pos] = s.w | ((d.w & 511) << 17);
        }
    }
    __syncthreads();
    if (tid < NBUCK) {                                 // sentinel-fill pad slots
        int endReal = lcur[tid];
        int endPad  = soff[tid] + (((lhist[tid]) + 15) & ~15);
        for (int k = endReal; k < endPad; ++k) stage[k] = -1;
    }
    __syncthreads();
    int wv = tid >> 6, ln = tid & 63;                  // full-line writeback
    for (int b = wv; b < NBUCK; b += 16) {
        int np = (lhist[b] + 15) & ~15;
        int so = soff[b], gb = gbase[b];
        for (int k = ln; k < np; k += 64)
            ebuf[gb + k] = stage[so + k];
    }
}

// ---- bucketsort: 512-node buckets, count, scan, place into LDS, ------------
// ---- coalesced full-line writeback; xs bf16 conversion fused at the end ----
__global__ __launch_bounds__(1024) void bucketsort_kernel(const int* __restrict__ gcursor,
        int* __restrict__ ebuf, int* __restrict__ rowStart, int* __restrict__ rowEnd,
        float* __restrict__ dinv, const float* __restrict__ x,
        unsigned int* __restrict__ xsb, float* __restrict__ zs) {
    __shared__ int   cnt[BNODES];
    __shared__ int   cur[BNODES];
    __shared__ float dls[BNODES];
    __shared__ int   stage[CAP];                       // 75.8 KB
    __shared__ int   szp_sh;
    int b = blockIdx.x, tid = threadIdx.x;
    if (tid < BNODES) cnt[tid] = 0;
    __syncthreads();
    int base = b * CAP;
    int size = gcursor[b];                             // incl. partition pads

    for (int j = tid; j < size; j += 1024) {           // pass 1: count
        unsigned p = (unsigned)ebuf[base + j];
        if (p != 0xFFFFFFFFu) atomicAdd(&cnt[p >> 17], 1);
    }
    __syncthreads();

    int v = 0, vp = 0;
    if (tid < BNODES) { v = cnt[tid]; vp = (v + 7) & ~7; cur[tid] = vp; }
    __syncthreads();
    for (int off = 1; off < BNODES; off <<= 1) {       // inclusive scan of vp
        int t = 0;
        if (tid < BNODES && tid >= off) t = cur[tid - off];
        __syncthreads();
        if (tid < BNODES) cur[tid] += t;
        __syncthreads();
    }
    if (tid < BNODES) {
        int excl = cur[tid] - vp;
        int node = b * BNODES + tid;
        if (node < N_NODES) {
            rowStart[node] = base + excl;
            rowEnd[node]   = base + excl + vp;         // padded end
            float dn = rsqrtf((float)v + 1.0f);        // +1 = self loop (REAL deg)
            dinv[node] = dn;
            dls[tid] = dn;
        }
        if (tid == BNODES - 1) szp_sh = cur[tid];      // total node-padded size
        cur[tid] = excl;                               // becomes cursor
        for (int p2 = excl + v; p2 < excl + vp; ++p2)  // fill node-pad slots
            stage[p2] = N_NODES;                       // sentinel -> zero row
    }
    __syncthreads();

    for (int j = tid; j < size; j += 1024) {           // pass 2: place into LDS
        unsigned p = (unsigned)ebuf[base + j];
        if (p != 0xFFFFFFFFu) {
            int pos = atomicAdd(&cur[p >> 17], 1);
            stage[pos] = p & 0x1FFFF;
        }
    }
    __syncthreads();
    int szp = szp_sh;
    for (int j = tid; j < szp; j += 1024)              // coalesced writeback
        ebuf[base + j] = stage[j];

    // xs = bf16(x * dinv), padded to 32 features; 2 features per uint
    for (int i = tid; i < BNODES * 16; i += 1024) {
        int dl = i >> 4, kp = i & 15;
        int nd = b * BNODES + dl;
        if (nd < N_NODES) {
            float dn = dls[dl];
            int k0 = kp * 2, k1 = k0 + 1;
            float f0 = (k0 < IN_DIM) ? x[nd * IN_DIM + k0] * dn : 0.0f;
            float f1 = (k1 < IN_DIM) ? x[nd * IN_DIM + k1] * dn : 0.0f;
            xsb[(size_t)nd * 16 + kp] = (unsigned)f2bf(f0) | ((unsigned)f2bf(f1) << 16);
        } else if (nd == N_NODES) {
            xsb[(size_t)nd * 16 + kp] = 0u;            // sentinel zero row
        }
    }
    if (b == 0 && tid == 0) {                          // zs sentinel (agg2 pads)
        zs[2 * N_NODES]     = 0.0f;
        zs[2 * N_NODES + 1] = 0.0f;
    }
}

// --- fused (round-6 proven): 8 streams x 8 lanes, quad window, 4 nodes/wave -
#define XROW(i) (((unsigned)(i) << 6) | moff)

#define PREP(P, rs, re, node)                                            \
    int P##i0, P##i1, P##i2, P##i3, P##i4, P##i5;                        \
    {                                                                    \
        int relim = max((re) - 1, (rs));                                 \
        int j0 = (rs) + q;                                               \
        int t0 = ebuf[min(j0,      relim)];                              \
        int t1 = ebuf[min(j0 + 8,  relim)];                              \
        int t2 = ebuf[min(j0 + 16, relim)];                              \
        int t3 = ebuf[min(j0 + 24, relim)];                              \
        int t4 = ebuf[min(j0 + 32, relim)];                              \
        P##i0 = (j0      < (re)) ? t0 : N_NODES;                         \
        P##i1 = (j0 + 8  < (re)) ? t1 : N_NODES;                         \
        P##i2 = (j0 + 16 < (re)) ? t2 : N_NODES;                         \
        P##i3 = (j0 + 24 < (re)) ? t3 : N_NODES;                         \
        P##i4 = (j0 + 32 < (re)) ? t4 : N_NODES;                         \
        P##i5 = (q == 0) ? (node) : N_NODES;   /* self loop as slot 6 */ \
    }

#define GATH(G, P)                                                       \
    uint2 G##0 = *(const uint2*)(xb + XROW(P##i0));                      \
    uint2 G##1 = *(const uint2*)(xb + XROW(P##i1));                      \
    uint2 G##2 = *(const uint2*)(xb + XROW(P##i2));                      \
    uint2 G##3 = *(const uint2*)(xb + XROW(P##i3));                      \
    uint2 G##4 = *(const uint2*)(xb + XROW(P##i4));                      \
    uint2 G##5 = *(const uint2*)(xb + XROW(P##i5));

#define UNP(acc, G)                                                      \
    unpack_add(acc, G##0); unpack_add(acc, G##1); unpack_add(acc, G##2); \
    unpack_add(acc, G##3); unpack_add(acc, G##4); unpack_add(acc, G##5);

#define TAIL(acc, rs, re)                                                \
    {                                                                    \
        int j = (rs) + q + 40;                                           \
        while (j < (re)) {            /* wave-uniform trip count */      \
            int s = ebuf[j];                                             \
            uint2 a = *(const uint2*)(xb + XROW(s));                     \
            unpack_add(acc, a);                                          \
            j += 8;                                                      \
        }                                                                \
    }

// two nodes' MLPs fused: shared w1s reads, interleaved FMA chains
static __device__ __forceinline__ void mlp2_store(float4 aA, float4 aB,
        int nodeA, int nodeB, int lane,
        const float* w1s, const float* b1s, const float* w2s,
        const float* __restrict__ dinv, float* __restrict__ zs) {
    #pragma unroll
    for (int msk = 8; msk <= 32; msk <<= 1) {          // fold 8 streams (both)
        aA.x += __shfl_xor(aA.x, msk); aB.x += __shfl_xor(aB.x, msk);
        aA.y += __shfl_xor(aA.y, msk); aB.y += __shfl_xor(aB.y, msk);
        aA.z += __shfl_xor(aA.z, msk); aB.z += __shfl_xor(aB.z, msk);
        aA.w += __shfl_xor(aA.w, msk); aB.w += __shfl_xor(aB.w, msk);
    }
    float dnA = dinv[nodeA], dnB = dinv[nodeB];
    aA.x *= dnA; aA.y *= dnA; aA.z *= dnA; aA.w *= dnA;
    aB.x *= dnB; aB.y *= dnB; aB.z *= dnB; aB.w *= dnB;

    float hA = b1s[lane], hB = b1s[lane];
    #pragma unroll
    for (int kk = 0; kk < IN_DIM; ++kk) {              // shared weight read
        float w = w1s[kk * HID_DIM + lane];
        float cA = ((kk & 3) == 0) ? aA.x : ((kk & 3) == 1) ? aA.y
                 : ((kk & 3) == 2) ? aA.z : aA.w;
        float cB = ((kk & 3) == 0) ? aB.x : ((kk & 3) == 1) ? aB.y
                 : ((kk & 3) == 2) ? aB.z : aB.w;
        hA = fmaf(__shfl(cA, kk >> 2), w, hA);
        hB = fmaf(__shfl(cB, kk >> 2), w, hB);
    }
    hA = fmaxf(hA, 0.0f); hB = fmaxf(hB, 0.0f);

    float zA0 = hA * w2s[lane * 2 + 0], zA1 = hA * w2s[lane * 2 + 1];
    float zB0 = hB * w2s[lane * 2 + 0], zB1 = hB * w2s[lane * 2 + 1];
    #pragma unroll
    for (int off = 32; off > 0; off >>= 1) {
        zA0 += __shfl_down(zA0, off); zA1 += __shfl_down(zA1, off);
        zB0 += __shfl_down(zB0, off); zB1 += __shfl_down(zB1, off);
    }
    if (lane == 0) {                                   // pre-scale by src dinv
        float2 oA; oA.x = zA0 * dnA; oA.y = zA1 * dnA;
        float2 oB; oB.x = zB0 * dnB; oB.y = zB1 * dnB;
        *(float2*)(zs + nodeA * 2) = oA;
        *(float2*)(zs + nodeB * 2) = oB;
    }
}

__global__ __launch_bounds__(512) void fused_kernel(const unsigned int* __restrict__ xs_,
        const int* __restrict__ rowStart, const int* __restrict__ rowEnd,
        const int* __restrict__ ebuf, const float* __restrict__ dinv,
        const float* __restrict__ W1, const float* __restrict__ b1,
        const float* __restrict__ W2, float* __restrict__ zs, int nbase) {
    __shared__ float w1s[IN_DIM * HID_DIM];
    __shared__ float b1s[HID_DIM];
    __shared__ float w2s[HID_DIM * 2];
    const int tid = threadIdx.x;
    for (int i = tid; i < IN_DIM * HID_DIM; i += 512) w1s[i] = W1[i];
    if (tid < HID_DIM) {
        b1s[tid] = b1[tid];
        w2s[tid * 2 + 0] = W2[tid * 2 + 0];
        w2s[tid * 2 + 1] = W2[tid * 2 + 1];
    }
    __syncthreads();

    const int lane = tid & 63;
    const int q = lane >> 3, m = lane & 7;             // 8 streams x 8 lanes
    const unsigned moff = (unsigned)(m << 3);          // byte offset in 64B row
    const char* xb = (const char*)xs_;
    const int n0 = nbase + blockIdx.x * 32 + (tid >> 6) * 4;  // 8 waves x 4 nodes

    const int rs0 = rowStart[n0+0], re0 = rowEnd[n0+0];
    const int rs1 = rowStart[n0+1], re1 = rowEnd[n0+1];
    const int rs2 = rowStart[n0+2], re2 = rowEnd[n0+2];
    const int rs3 = rowStart[n0+3], re3 = rowEnd[n0+3];

    // ---- one latency window: all 20 idx loads, then all 24 gathers --------
    PREP(pa, rs0, re0, n0+0)
    PREP(pb, rs1, re1, n0+1)
    PREP(pc, rs2, re2, n0+2)
    PREP(pd, rs3, re3, n0+3)
    GATH(ga, pa)
    GATH(gb, pb)
    GATH(gc, pc)
    GATH(gd, pd)                                       // 24 gathers in flight

    float4 acc0 = make_float4(0.f, 0.f, 0.f, 0.f);
    float4 acc1 = make_float4(0.f, 0.f, 0.f, 0.f);
    float4 acc2 = make_float4(0.f, 0.f, 0.f, 0.f);
    float4 acc3 = make_float4(0.f, 0.f, 0.f, 0.f);
    UNP(acc0, ga)
    TAIL(acc0, rs0, re0)
    UNP(acc1, gb)
    TAIL(acc1, rs1, re1)
    UNP(acc2, gc)
    TAIL(acc2, rs2, re2)
    UNP(acc3, gd)
    TAIL(acc3, rs3, re3)
    mlp2_store(acc0, acc1, n0+0, n0+1, lane, w1s, b1s, w2s, dinv, zs);
    mlp2_store(acc2, acc3, n0+2, n0+3, lane, w1s, b1s, w2s, dinv, zs);
}

// ------- agg2: 16-lane group per node gathers zs (2x unroll) + finalize -----
__global__ __launch_bounds__(256) void agg2_kernel(const float* __restrict__ zs,
        const int* __restrict__ rowStart, const int* __restrict__ rowEnd,
        const int* __restrict__ ebuf, const float* __restrict__ dinv,
        const float* __restrict__ b2, float* __restrict__ out) {
    int tid = threadIdx.x;
    int node = blockIdx.x * 16 + (tid >> 4);
    if (node >= N_NODES) return;
    int gl = tid & 15;
    const float2* zs2 = (const float2*)zs;
    float a0 = 0.0f, a1 = 0.0f, c0 = 0.0f, c1 = 0.0f;
    int rs = rowStart[node], re = rowEnd[node];
    int j = rs + gl;
    for (; j + 16 < re; j += 32) {
        float2 za = zs2[ebuf[j]];
        float2 zb = zs2[ebuf[j + 16]];
        a0 += za.x; a1 += za.y;
        c0 += zb.x; c1 += zb.y;
    }
    if (j < re) {
        float2 za = zs2[ebuf[j]];
        a0 += za.x; a1 += za.y;
    }
    a0 += c0; a1 += c1;
    a0 += __shfl_xor(a0, 8); a1 += __shfl_xor(a1, 8);
    a0 += __shfl_xor(a0, 4); a1 += __shfl_xor(a1, 4);
    a0 += __shfl_xor(a0, 2); a1 += __shfl_xor(a1, 2);
    a0 += __shfl_xor(a0, 1); a1 += __shfl_xor(a1, 1);
    if (gl == 0) {
        float dn = dinv[node];
        float2 zself = zs2[node];
        float2 o;
        o.x = dn * (a0 + zself.x) + b2[0];
        o.y = dn * (a1 + zself.y) + b2[1];
        ((float2*)out)[node] = o;
    }
}

extern "C" void kernel_launch(void* const* d_in, const int* in_sizes, int n_in,
                              void* d_out, int out_size, void* d_ws, size_t ws_size,
                              hipStream_t stream) {
    const float* x  = (const float*)d_in[0];
    const int*   ei = (const int*)d_in[1];
    const float* W1 = (const float*)d_in[2];
    const float* b1 = (const float*)d_in[3];
    const float* W2 = (const float*)d_in[4];
    const float* b2 = (const float*)d_in[5];
    float* out = (float*)d_out;

    int*   wsi      = (int*)d_ws;
    float* wsf      = (float*)d_ws;
    int*   gcursor  = wsi + OFF_CUR;
    int*   rowStart = wsi + OFF_ROWS;
    int*   rowEnd   = wsi + OFF_ROWE;
    float* dinv     = wsf + OFF_DINV;
    float* zs       = wsf + OFF_ZS;
    int*   ebuf     = wsi + OFF_EBUF;
    unsigned int* xsb = (unsigned int*)(wsi + OFF_XS);

    hipMemsetAsync(gcursor, 0, NBUCK * sizeof(int), stream);
    partition_kernel<<<(N_EDGES + PEPB - 1) / PEPB, 1024, 0, stream>>>(ei, gcursor, ebuf);
    bucketsort_kernel<<<NBUCK, 1024, 0, stream>>>(gcursor, ebuf, rowStart, rowEnd, dinv, x, xsb, zs);
    // split fused into two half-grid launches: reveals other kernels in top-5
    fused_kernel<<<1563, 512, 0, stream>>>(xsb, rowStart, rowEnd, ebuf, dinv, W1, b1, W2, zs, 0);
    fused_kernel<<<1562, 512, 0, stream>>>(xsb, rowStart, rowEnd, ebuf, dinv, W1, b1, W2, zs, 50016);
    agg2_kernel<<<(N_NODES + 15) / 16, 256, 0, stream>>>(zs, rowStart, rowEnd, ebuf, dinv, b2, out);
}

// Round 10
// 201.382 us; speedup vs baseline: 1.1144x; 1.0691x over previous
//
#include <hip/hip_runtime.h>

#define N_NODES 100000
#define N_EDGES 3200000
#define IN_DIM  29
#define HID_DIM 64
#define NBUCK   391            // ceil(N / 256)
#define BNODES  256            // dst nodes per bucket
#define CAP     10496          // slots/bucket (mult of 16); mean ~9650, +7.6 sigma
#define PEPT    16
#define PEPB    16384          // 1024 threads * 16 edges
#define PSTAGE  22272          // >= NBUCK*15 + PEPB = 22249

// ---- ws layout (4-byte units) ---------------------------------------------
#define OFF_CUR   0            // gcursor[NBUCK] (pad to 512)
#define OFF_ROWS  512          // rowStart[N]
#define OFF_ROWE  100512       // rowEnd[N]  (PADDED end)
#define OFF_DINV  200512       // dinv[N]
#define OFF_ZS    300512       // zs[2N+2]; row N = sentinel zeros
#define OFF_EBUF  500544       // ebuf[NBUCK*CAP] = 4,103,936
#define OFF_XS    4604480      // xs bf16[(N+1) rows * 16 uints], 128B aligned

static __device__ __forceinline__ unsigned short f2bf(float f) {
    unsigned u = __float_as_uint(f);
    u += 0x7fffu + ((u >> 16) & 1u);   // RNE
    return (unsigned short)(u >> 16);
}

static __device__ __forceinline__ void unpack_add(float4& acc, uint2 a) {
    acc.x += __uint_as_float(a.x << 16);
    acc.y += __uint_as_float(a.x & 0xFFFF0000u);
    acc.z += __uint_as_float(a.y << 16);
    acc.w += __uint_as_float(a.y & 0xFFFF0000u);
}

// -- partition: SINGLE ei read (edges held in registers across the scan), ----
// -- LDS counting-sort per block, FULL-LINE coalesced writeback. Pads = -1. --
__global__ __launch_bounds__(1024) void partition_kernel(const int* __restrict__ ei,
        int* __restrict__ gcursor, int* __restrict__ ebuf) {
    __shared__ int lhist[NBUCK];
    __shared__ int lcur[NBUCK];
    __shared__ int gbase[NBUCK];
    __shared__ int soff[NBUCK];
    __shared__ int sc[NBUCK];
    __shared__ int stage[PSTAGE];                      // 87 KB
    int tid = threadIdx.x;
    for (int i = tid; i < NBUCK; i += 1024) lhist[i] = 0;
    __syncthreads();

    int base = blockIdx.x * PEPB + tid * PEPT;         // 16-aligned; E%16==0
    bool valid = (base < N_EDGES);
    int dv[PEPT], sv[PEPT];                            // carried in registers
    if (valid) {                                       // pass 1: load + hist
        const int4* dp = (const int4*)(ei + N_EDGES + base);
        const int4* sp = (const int4*)(ei + base);
        #pragma unroll
        for (int q = 0; q < 4; ++q) {
            int4 d = dp[q];
            dv[4*q+0] = d.x; dv[4*q+1] = d.y; dv[4*q+2] = d.z; dv[4*q+3] = d.w;
            int4 s = sp[q];
            sv[4*q+0] = s.x; sv[4*q+1] = s.y; sv[4*q+2] = s.z; sv[4*q+3] = s.w;
        }
        #pragma unroll
        for (int j = 0; j < PEPT; ++j) atomicAdd(&lhist[dv[j] >> 8], 1);
    }
    __syncthreads();
    int c = 0, p = 0;                                  // scan 16-padded counts
    if (tid < NBUCK) { c = lhist[tid]; p = (c + 15) & ~15; sc[tid] = p; }
    __syncthreads();
    for (int off = 1; off < NBUCK; off <<= 1) {
        int t = 0;
        if (tid < NBUCK && tid >= off) t = sc[tid - off];
        __syncthreads();
        if (tid < NBUCK) sc[tid] += t;
        __syncthreads();
    }
    if (tid < NBUCK) {
        int so = sc[tid] - p;
        soff[tid] = so;
        lcur[tid] = so;
        gbase[tid] = p ? (tid * CAP + atomicAdd(&gcursor[tid], p)) : 0; // 64B-aligned claim
    }
    __syncthreads();
    if (valid) {                                       // pass 2: place (regs)
        #pragma unroll
        for (int j = 0; j < PEPT; ++j) {
            int d = dv[j];
            int pos = atomicAdd(&lcur[d >> 8], 1);
            stage[pos] = sv[j] | ((d & 255) << 17);    // src < 2^17
        }
    }
    __syncthreads();
    if (tid < NBUCK) {                                 // sentinel-fill pad slots
        int endReal = lcur[tid];
        int endPad  = soff[tid] + (((lhist[tid]) + 15) & ~15);
        for (int k = endReal; k < endPad; ++k) stage[k] = -1;
    }
    __syncthreads();
    int wv = tid >> 6, ln = tid & 63;                  // full-line writeback
    for (int b = wv; b < NBUCK; b += 16) {
        int np = (lhist[b] + 15) & ~15;
        int so = soff[b], gb = gbase[b];
        for (int k = ln; k < np; k += 64)
            ebuf[gb + k] = stage[so + k];
    }
}

// ---- bucketsort (round-6 proven): count, scan, place into LDS, -------------
// ---- coalesced full-line writeback; xs bf16 conversion fused at the end ----
__global__ __launch_bounds__(1024) void bucketsort_kernel(const int* __restrict__ gcursor,
        int* __restrict__ ebuf, int* __restrict__ rowStart, int* __restrict__ rowEnd,
        float* __restrict__ dinv, const float* __restrict__ x,
        unsigned int* __restrict__ xsb, float* __restrict__ zs) {
    __shared__ int   cnt[BNODES];
    __shared__ int   cur[BNODES];
    __shared__ float dls[BNODES];
    __shared__ int   stage[CAP];                       // 41 KB
    __shared__ int   szp_sh;
    int b = blockIdx.x, tid = threadIdx.x;
    if (tid < BNODES) cnt[tid] = 0;
    __syncthreads();
    int base = b * CAP;
    int size = gcursor[b];                             // incl. partition pads

    for (int j = tid; j < size; j += 1024) {           // pass 1: count
        unsigned p = (unsigned)ebuf[base + j];
        if (p != 0xFFFFFFFFu) atomicAdd(&cnt[p >> 17], 1);
    }
    __syncthreads();

    int v = 0, vp = 0;
    if (tid < BNODES) { v = cnt[tid]; vp = (v + 7) & ~7; cur[tid] = vp; }
    __syncthreads();
    for (int off = 1; off < BNODES; off <<= 1) {       // inclusive scan of vp
        int t = 0;
        if (tid < BNODES && tid >= off) t = cur[tid - off];
        __syncthreads();
        if (tid < BNODES) cur[tid] += t;
        __syncthreads();
    }
    if (tid < BNODES) {
        int excl = cur[tid] - vp;
        int node = b * BNODES + tid;
        if (node < N_NODES) {
            rowStart[node] = base + excl;
            rowEnd[node]   = base + excl + vp;         // padded end
            float dn = rsqrtf((float)v + 1.0f);        // +1 = self loop (REAL deg)
            dinv[node] = dn;
            dls[tid] = dn;
        }
        if (tid == BNODES - 1) szp_sh = cur[tid];      // total node-padded size
        cur[tid] = excl;                               // becomes cursor
        for (int p2 = excl + v; p2 < excl + vp; ++p2)  // fill node-pad slots
            stage[p2] = N_NODES;                       // sentinel -> zero row
    }
    __syncthreads();

    for (int j = tid; j < size; j += 1024) {           // pass 2: place into LDS
        unsigned p = (unsigned)ebuf[base + j];
        if (p != 0xFFFFFFFFu) {
            int pos = atomicAdd(&cur[p >> 17], 1);
            stage[pos] = p & 0x1FFFF;
        }
    }
    __syncthreads();
    int szp = szp_sh;
    for (int j = tid; j < szp; j += 1024)              // coalesced writeback
        ebuf[base + j] = stage[j];

    // xs = bf16(x * dinv), padded to 32 features; 2 features per uint
    for (int i = tid; i < BNODES * 16; i += 1024) {
        int dl = i >> 4, kp = i & 15;
        int nd = b * BNODES + dl;
        if (nd < N_NODES) {
            float dn = dls[dl];
            int k0 = kp * 2, k1 = k0 + 1;
            float f0 = (k0 < IN_DIM) ? x[nd * IN_DIM + k0] * dn : 0.0f;
            float f1 = (k1 < IN_DIM) ? x[nd * IN_DIM + k1] * dn : 0.0f;
            xsb[(size_t)nd * 16 + kp] = (unsigned)f2bf(f0) | ((unsigned)f2bf(f1) << 16);
        } else if (nd == N_NODES) {
            xsb[(size_t)nd * 16 + kp] = 0u;            // sentinel zero row
        }
    }
    if (b == 0 && tid == 0) {                          // zs sentinel (agg2 pads)
        zs[2 * N_NODES]     = 0.0f;
        zs[2 * N_NODES + 1] = 0.0f;
    }
}

// --- fused (round-6 proven): 8 streams x 8 lanes, quad window, 4 nodes/wave -
#define XROW(i) (((unsigned)(i) << 6) | moff)

#define PREP(P, rs, re, node)                                            \
    int P##i0, P##i1, P##i2, P##i3, P##i4, P##i5;                        \
    {                                                                    \
        int relim = max((re) - 1, (rs));                                 \
        int j0 = (rs) + q;                                               \
        int t0 = ebuf[min(j0,      relim)];                              \
        int t1 = ebuf[min(j0 + 8,  relim)];                              \
        int t2 = ebuf[min(j0 + 16, relim)];                              \
        int t3 = ebuf[min(j0 + 24, relim)];                              \
        int t4 = ebuf[min(j0 + 32, relim)];                              \
        P##i0 = (j0      < (re)) ? t0 : N_NODES;                         \
        P##i1 = (j0 + 8  < (re)) ? t1 : N_NODES;                         \
        P##i2 = (j0 + 16 < (re)) ? t2 : N_NODES;                         \
        P##i3 = (j0 + 24 < (re)) ? t3 : N_NODES;                         \
        P##i4 = (j0 + 32 < (re)) ? t4 : N_NODES;                         \
        P##i5 = (q == 0) ? (node) : N_NODES;   /* self loop as slot 6 */ \
    }

#define GATH(G, P)                                                       \
    uint2 G##0 = *(const uint2*)(xb + XROW(P##i0));                      \
    uint2 G##1 = *(const uint2*)(xb + XROW(P##i1));                      \
    uint2 G##2 = *(const uint2*)(xb + XROW(P##i2));                      \
    uint2 G##3 = *(const uint2*)(xb + XROW(P##i3));                      \
    uint2 G##4 = *(const uint2*)(xb + XROW(P##i4));                      \
    uint2 G##5 = *(const uint2*)(xb + XROW(P##i5));

#define UNP(acc, G)                                                      \
    unpack_add(acc, G##0); unpack_add(acc, G##1); unpack_add(acc, G##2); \
    unpack_add(acc, G##3); unpack_add(acc, G##4); unpack_add(acc, G##5);

#define TAIL(acc, rs, re)                                                \
    {                                                                    \
        int j = (rs) + q + 40;                                           \
        while (j < (re)) {            /* wave-uniform trip count */      \
            int s = ebuf[j];                                             \
            uint2 a = *(const uint2*)(xb + XROW(s));                     \
            unpack_add(acc, a);                                          \
            j += 8;                                                      \
        }                                                                \
    }

// two nodes' MLPs fused: shared w1s reads, interleaved FMA chains
static __device__ __forceinline__ void mlp2_store(float4 aA, float4 aB,
        int nodeA, int nodeB, int lane,
        const float* w1s, const float* b1s, const float* w2s,
        const float* __restrict__ dinv, float* __restrict__ zs) {
    #pragma unroll
    for (int msk = 8; msk <= 32; msk <<= 1) {          // fold 8 streams (both)
        aA.x += __shfl_xor(aA.x, msk); aB.x += __shfl_xor(aB.x, msk);
        aA.y += __shfl_xor(aA.y, msk); aB.y += __shfl_xor(aB.y, msk);
        aA.z += __shfl_xor(aA.z, msk); aB.z += __shfl_xor(aB.z, msk);
        aA.w += __shfl_xor(aA.w, msk); aB.w += __shfl_xor(aB.w, msk);
    }
    float dnA = dinv[nodeA], dnB = dinv[nodeB];
    aA.x *= dnA; aA.y *= dnA; aA.z *= dnA; aA.w *= dnA;
    aB.x *= dnB; aB.y *= dnB; aB.z *= dnB; aB.w *= dnB;

    float hA = b1s[lane], hB = b1s[lane];
    #pragma unroll
    for (int kk = 0; kk < IN_DIM; ++kk) {              // shared weight read
        float w = w1s[kk * HID_DIM + lane];
        float cA = ((kk & 3) == 0) ? aA.x : ((kk & 3) == 1) ? aA.y
                 : ((kk & 3) == 2) ? aA.z : aA.w;
        float cB = ((kk & 3) == 0) ? aB.x : ((kk & 3) == 1) ? aB.y
                 : ((kk & 3) == 2) ? aB.z : aB.w;
        hA = fmaf(__shfl(cA, kk >> 2), w, hA);
        hB = fmaf(__shfl(cB, kk >> 2), w, hB);
    }
    hA = fmaxf(hA, 0.0f); hB = fmaxf(hB, 0.0f);

    float zA0 = hA * w2s[lane * 2 + 0], zA1 = hA * w2s[lane * 2 + 1];
    float zB0 = hB * w2s[lane * 2 + 0], zB1 = hB * w2s[lane * 2 + 1];
    #pragma unroll
    for (int off = 32; off > 0; off >>= 1) {
        zA0 += __shfl_down(zA0, off); zA1 += __shfl_down(zA1, off);
        zB0 += __shfl_down(zB0, off); zB1 += __shfl_down(zB1, off);
    }
    if (lane == 0) {                                   // pre-scale by src dinv
        float2 oA; oA.x = zA0 * dnA; oA.y = zA1 * dnA;
        float2 oB; oB.x = zB0 * dnB; oB.y = zB1 * dnB;
        *(float2*)(zs + nodeA * 2) = oA;
        *(float2*)(zs + nodeB * 2) = oB;
    }
}

__global__ __launch_bounds__(512) void fused_kernel(const unsigned int* __restrict__ xs_,
        const int* __restrict__ rowStart, const int* __restrict__ rowEnd,
        const int* __restrict__ ebuf, const float* __restrict__ dinv,
        const float* __restrict__ W1, const float* __restrict__ b1,
        const float* __restrict__ W2, float* __restrict__ zs) {
    __shared__ float w1s[IN_DIM * HID_DIM];
    __shared__ float b1s[HID_DIM];
    __shared__ float w2s[HID_DIM * 2];
    const int tid = threadIdx.x;
    for (int i = tid; i < IN_DIM * HID_DIM; i += 512) w1s[i] = W1[i];
    if (tid < HID_DIM) {
        b1s[tid] = b1[tid];
        w2s[tid * 2 + 0] = W2[tid * 2 + 0];
        w2s[tid * 2 + 1] = W2[tid * 2 + 1];
    }
    __syncthreads();

    const int lane = tid & 63;
    const int q = lane >> 3, m = lane & 7;             // 8 streams x 8 lanes
    const unsigned moff = (unsigned)(m << 3);          // byte offset in 64B row
    const char* xb = (const char*)xs_;
    const int n0 = blockIdx.x * 32 + (tid >> 6) * 4;   // 8 waves x 4 nodes; 3125*32=N

    const int rs0 = rowStart[n0+0], re0 = rowEnd[n0+0];
    const int rs1 = rowStart[n0+1], re1 = rowEnd[n0+1];
    const int rs2 = rowStart[n0+2], re2 = rowEnd[n0+2];
    const int rs3 = rowStart[n0+3], re3 = rowEnd[n0+3];

    // ---- one latency window: all 20 idx loads, then all 24 gathers --------
    PREP(pa, rs0, re0, n0+0)
    PREP(pb, rs1, re1, n0+1)
    PREP(pc, rs2, re2, n0+2)
    PREP(pd, rs3, re3, n0+3)
    GATH(ga, pa)
    GATH(gb, pb)
    GATH(gc, pc)
    GATH(gd, pd)                                       // 24 gathers in flight

    float4 acc0 = make_float4(0.f, 0.f, 0.f, 0.f);
    float4 acc1 = make_float4(0.f, 0.f, 0.f, 0.f);
    float4 acc2 = make_float4(0.f, 0.f, 0.f, 0.f);
    float4 acc3 = make_float4(0.f, 0.f, 0.f, 0.f);
    UNP(acc0, ga)
    TAIL(acc0, rs0, re0)
    UNP(acc1, gb)
    TAIL(acc1, rs1, re1)
    UNP(acc2, gc)
    TAIL(acc2, rs2, re2)
    UNP(acc3, gd)
    TAIL(acc3, rs3, re3)
    mlp2_store(acc0, acc1, n0+0, n0+1, lane, w1s, b1s, w2s, dinv, zs);
    mlp2_store(acc2, acc3, n0+2, n0+3, lane, w1s, b1s, w2s, dinv, zs);
}

// ------- agg2: 16-lane group per node gathers zs (2x unroll) + finalize -----
// 512 threads = 32 nodes/block; grid exact (3125 * 32 = 100000), no check.
__global__ __launch_bounds__(512) void agg2_kernel(const float* __restrict__ zs,
        const int* __restrict__ rowStart, const int* __restrict__ rowEnd,
        const int* __restrict__ ebuf, const float* __restrict__ dinv,
        const float* __restrict__ b2, float* __restrict__ out) {
    int tid = threadIdx.x;
    int node = blockIdx.x * 32 + (tid >> 4);
    int gl = tid & 15;
    const float2* zs2 = (const float2*)zs;
    float a0 = 0.0f, a1 = 0.0f, c0 = 0.0f, c1 = 0.0f;
    int rs = rowStart[node], re = rowEnd[node];
    int j = rs + gl;
    for (; j + 16 < re; j += 32) {
        float2 za = zs2[ebuf[j]];
        float2 zb = zs2[ebuf[j + 16]];
        a0 += za.x; a1 += za.y;
        c0 += zb.x; c1 += zb.y;
    }
    if (j < re) {
        float2 za = zs2[ebuf[j]];
        a0 += za.x; a1 += za.y;
    }
    a0 += c0; a1 += c1;
    a0 += __shfl_xor(a0, 8); a1 += __shfl_xor(a1, 8);
    a0 += __shfl_xor(a0, 4); a1 += __shfl_xor(a1, 4);
    a0 += __shfl_xor(a0, 2); a1 += __shfl_xor(a1, 2);
    a0 += __shfl_xor(a0, 1); a1 += __shfl_xor(a1, 1);
    if (gl == 0) {
        float dn = dinv[node];
        float2 zself = zs2[node];
        float2 o;
        o.x = dn * (a0 + zself.x) + b2[0];
        o.y = dn * (a1 + zself.y) + b2[1];
        ((float2*)out)[node] = o;
    }
}

extern "C" void kernel_launch(void* const* d_in, const int* in_sizes, int n_in,
                              void* d_out, int out_size, void* d_ws, size_t ws_size,
                              hipStream_t stream) {
    const float* x  = (const float*)d_in[0];
    const int*   ei = (const int*)d_in[1];
    const float* W1 = (const float*)d_in[2];
    const float* b1 = (const float*)d_in[3];
    const float* W2 = (const float*)d_in[4];
    const float* b2 = (const float*)d_in[5];
    float* out = (float*)d_out;

    int*   wsi      = (int*)d_ws;
    float* wsf      = (float*)d_ws;
    int*   gcursor  = wsi + OFF_CUR;
    int*   rowStart = wsi + OFF_ROWS;
    int*   rowEnd   = wsi + OFF_ROWE;
    float* dinv     = wsf + OFF_DINV;
    float* zs       = wsf + OFF_ZS;
    int*   ebuf     = wsi + OFF_EBUF;
    unsigned int* xsb = (unsigned int*)(wsi + OFF_XS);

    hipMemsetAsync(gcursor, 0, NBUCK * sizeof(int), stream);
    partition_kernel<<<(N_EDGES + PEPB - 1) / PEPB, 1024, 0, stream>>>(ei, gcursor, ebuf);
    bucketsort_kernel<<<NBUCK, 1024, 0, stream>>>(gcursor, ebuf, rowStart, rowEnd, dinv, x, xsb, zs);
    fused_kernel<<<N_NODES / 32, 512, 0, stream>>>(xsb, rowStart, rowEnd, ebuf, dinv, W1, b1, W2, zs);
    agg2_kernel<<<N_NODES / 32, 512, 0, stream>>>(zs, rowStart, rowEnd, ebuf, dinv, b2, out);
}